// Round 8
// baseline (175.136 us; speedup 1.0000x reference)
//
#include <hip/hip_runtime.h>
#include <math.h>

#define GRID_CELLS 49
#define NOBJ 10
#define BB 2
#define NCLS 20
#define OUT_C 30   // 5*BB + NCLS
#define LAMBDA_C 5.0f
#define LAMBDA_N 0.5f
#define BLOCK 256
#define WAVES (BLOCK / 64)
#define CELLW 10               // gt stride: gcd(10,32)=2 -> 2-way conflict = free (m136)
#define ROWW (GRID_CELLS * OUT_C)  // 1470 floats per item

// One WAVE per batch item: barrier-free wave-private LDS staging.
// r6 bottleneck was scattered 120B-stride row loads (~12M cache-line
// requests); coalesced per-wave staging cuts that ~8x. No __syncthreads
// in the hot path (r5 showed barrier-coupled staging costs ~15us).
__global__ __launch_bounds__(BLOCK) void yolo_loss_wave(
    const float* __restrict__ outputs,
    const float* __restrict__ target,
    float* __restrict__ out,
    int batch, float inv_batch)
{
    __shared__ __align__(16) float rows[WAVES][ROWW];         // 4*5880 B
    __shared__ float gt[WAVES][GRID_CELLS][CELLW];            // 4*1960 B
    __shared__ float red[WAVES];

    const int t = threadIdx.x;
    const int w = t >> 6;
    const int lane = t & 63;
    const int b = blockIdx.x * WAVES + w;

    float lsum = 0.0f;
    if (b < batch) {
        // ---- coalesced stage: 735 float2, 12 wave-loads ----
        {
            const float2* src = reinterpret_cast<const float2*>(outputs + (size_t)b * ROWW);
            float2* dst = reinterpret_cast<float2*>(&rows[w][0]);
            #pragma unroll
            for (int i = 0; i < 12; ++i) {
                int idx = i * 64 + lane;
                if (idx < ROWW / 2) dst[idx] = src[idx];
            }
        }
        // ---- zero this wave's gt ----
        {
            float* gz = &gt[w][0][0];
            #pragma unroll
            for (int i = 0; i < 8; ++i) {
                int idx = i * 64 + lane;
                if (idx < GRID_CELLS * CELLW) gz[idx] = 0.0f;
            }
        }
        // ---- lanes 0..9: preprocess one target object each ----
        float t0 = 0.f, t1 = 0.f, t2f = 0.f, t3f = 0.f, t4 = 0.f;
        int cell = 0, nz = 0;
        if (lane < NOBJ) {
            const float* tp = target + (size_t)b * (NOBJ * 5) + lane * 5;
            t0 = tp[0]; t1 = tp[1];
            t2f = sqrtf(tp[2]); t3f = sqrtf(tp[3]);
            t4 = tp[4];
            if (t0 != t0)   t0  = -1.0f;
            if (t1 != t1)   t1  = -1.0f;
            if (t2f != t2f) t2f = -1.0f;
            if (t3f != t3f) t3f = -1.0f;
            if (t4 != t4)   t4  = -1.0f;
            int xi = (int)truncf(7.0f * t0);
            int yi = (int)truncf(7.0f * t1);
            cell = 7 * yi + xi;
            cell = cell < 0 ? 0 : (cell > GRID_CELLS - 1 ? GRID_CELLS - 1 : cell);
            bool valid = (t0 != -1.0f) && (xi >= 0);
            float s5 = t0 + t1 + t2f + t3f + t4;
            nz = (valid && (s5 > 0.0f)) ? 1 : 0;
        }
        // ---- slot assignment via wave shuffles (no LDS metadata) ----
        int slot = 0;
        #pragma unroll
        for (int p = 0; p < NOBJ - 1; ++p) {
            int cp = __shfl(cell, p, 64);
            int np = __shfl(nz, p, 64);
            if (p < lane && np && cp == cell) slot++;
        }
        if (lane < NOBJ && nz && slot < BB) {
            gt[w][cell][slot * 5 + 0] = t0;
            gt[w][cell][slot * 5 + 1] = t1;
            gt[w][cell][slot * 5 + 2] = t2f;
            gt[w][cell][slot * 5 + 3] = t3f;
            gt[w][cell][slot * 5 + 4] = t4;
        }
        // intra-wave DS is processed in order; drain so all lanes' reads
        // below see the staged rows + gt fills. No s_barrier needed.
        asm volatile("s_waitcnt lgkmcnt(0)" ::: "memory");

        // ---- lanes 0..48: per-cell loss (math verbatim from absmax-0 kernel) ----
        if (lane < GRID_CELLS) {
            const int c = lane;
            float g[BB][5];
            #pragma unroll
            for (int s = 0; s < BB; ++s)
                #pragma unroll
                for (int d = 0; d < 5; ++d) g[s][d] = gt[w][c][s * 5 + d];

            const float2* r2 = reinterpret_cast<const float2*>(&rows[w][c * OUT_C]);
            float pred[BB][5];
            {
                float2 p0 = r2[0], p1 = r2[1], p2 = r2[2], p3 = r2[3], p4 = r2[4];
                pred[0][0] = p0.x; pred[0][1] = p0.y; pred[0][2] = p1.x; pred[0][3] = p1.y; pred[0][4] = p2.x;
                pred[1][0] = p2.y; pred[1][1] = p3.x; pred[1][2] = p3.y; pred[1][3] = p4.x; pred[1][4] = p4.y;
            }
            float maxp; int cls;
            {
                float2 q0 = r2[5];
                maxp = q0.x; cls = 0;
                if (q0.y > maxp) { maxp = q0.y; cls = 1; }
                #pragma unroll
                for (int i = 1; i < NCLS / 2; ++i) {
                    float2 q = r2[5 + i];
                    if (q.x > maxp) { maxp = q.x; cls = 2 * i; }
                    if (q.y > maxp) { maxp = q.y; cls = 2 * i + 1; }
                }
            }
            float fcls = (float)cls;

            float pminx[BB], pmaxx[BB], pminy[BB], pmaxy[BB], parea[BB];
            #pragma unroll
            for (int p = 0; p < BB; ++p) {
                float sw = sqrtf(pred[p][2]);
                float sh = sqrtf(pred[p][3]);
                float w2 = sw * sw, h2 = sh * sh;
                pminx[p] = pred[p][0] - w2; pmaxx[p] = pred[p][0] + w2;
                pminy[p] = pred[p][1] - h2; pmaxy[p] = pred[p][1] + h2;
                parea[p] = fabsf(pmaxx[p] - pminx[p]) * fabsf(pmaxy[p] - pminy[p]);
            }
            float gminx[BB], gmaxx[BB], gminy[BB], gmaxy[BB], garea[BB];
            #pragma unroll
            for (int s = 0; s < BB; ++s) {
                float w2 = g[s][2] * g[s][2], h2 = g[s][3] * g[s][3];
                gminx[s] = g[s][0] - w2; gmaxx[s] = g[s][0] + w2;
                gminy[s] = g[s][1] - h2; gmaxy[s] = g[s][1] + h2;
                garea[s] = fabsf(gmaxx[s] - gminx[s]) * fabsf(gmaxy[s] - gminy[s]);
            }
            int t_index[BB];
            #pragma unroll
            for (int s = 0; s < BB; ++s) {
                float best = 0.0f; int bi = 0;
                #pragma unroll
                for (int p = 0; p < BB; ++p) {
                    float ix0 = fmaxf(gminx[s], pminx[p]);
                    float iy0 = fmaxf(gminy[s], pminy[p]);
                    float ix1 = fminf(gmaxx[s], pmaxx[p]);
                    float iy1 = fminf(gmaxy[s], pmaxy[p]);
                    float dx = fmaxf(ix1 - ix0, 0.0f);
                    float dy = fmaxf(iy1 - iy0, 0.0f);
                    float inter = dx * dy;
                    float uni = garea[s] + parea[p] - inter;
                    float iou = (uni == 0.0f) ? 0.0f : inter / uni;
                    if (p == 0) { best = iou; bi = 0; }
                    else if (iou > best) { best = iou; bi = p; }
                }
                t_index[s] = bi;
            }

            #pragma unroll
            for (int s = 0; s < BB; ++s) {
                float ga[5];
                #pragma unroll
                for (int d = 0; d < 5; ++d) ga[d] = (t_index[s] == 0) ? g[0][d] : g[1][d];
                float r1w = pred[s][2] * pred[s][2], r1h = pred[s][3] * pred[s][3];
                float r2w = ga[2] * ga[2],           r2h = ga[3] * ga[3];
                float min1x = pred[s][0] - 0.5f * r1w, max1x = pred[s][0] + 0.5f * r1w;
                float min1y = pred[s][1] - 0.5f * r1h, max1y = pred[s][1] + 0.5f * r1h;
                float min2x = ga[0] - 0.5f * r2w, max2x = ga[0] + 0.5f * r2w;
                float min2y = ga[1] - 0.5f * r2h, max2y = ga[1] + 0.5f * r2h;
                float dx = fmaxf(fminf(max1x, max2x) - fmaxf(min1x, min2x), 0.0f);
                float dy = fmaxf(fminf(max1y, max2y) - fmaxf(min1y, min2y), 0.0f);
                float inter2 = dx * dy;
                float uni2 = r1w * r1h + r2w * r2h - inter2;
                float conf;
                if (truncf(uni2) == 0.0f || truncf(inter2) == 0.0f) conf = 0.0f;
                else conf = truncf(inter2 / (uni2 == 0.0f ? 1.0f : uni2));
                #pragma unroll
                for (int d = 0; d < 4; ++d) {
                    float df = ga[d] - pred[s][d];
                    lsum += LAMBDA_C * df * df;
                }
                { float df = conf - pred[s][4]; lsum += df * df; }
                float m = 1.0f;
                if (b == batch - 1 && s == t_index[BB - 1]) m = 0.0f;
                float dn = (pred[s][4] - conf) * m;
                lsum += LAMBDA_N * dn * dn;
                float predn = maxp * pred[s][4];
                float truth = (conf == fcls) ? 1.0f : 0.0f;
                float sum5 = ga[0] + ga[1] + ga[2] + ga[3] + conf;
                float cm = (sum5 > 0.0f) ? 1.0f : ((sum5 < 0.0f) ? -1.0f : 0.0f);
                float dcl = truth - predn;
                lsum += cm * dcl * dcl;
            }
        }
    }

    // ---- block reduction: wave shuffle -> LDS -> one atomic per block ----
    #pragma unroll
    for (int off = 32; off > 0; off >>= 1) lsum += __shfl_down(lsum, off, 64);
    if (lane == 0) red[w] = lsum;
    __syncthreads();
    if (t == 0) {
        float s = 0.0f;
        #pragma unroll
        for (int v = 0; v < WAVES; ++v) s += red[v];
        atomicAdd(out, s * inv_batch);
    }
}

extern "C" void kernel_launch(void* const* d_in, const int* in_sizes, int n_in,
                              void* d_out, int out_size, void* d_ws, size_t ws_size,
                              hipStream_t stream) {
    const float* outputs = (const float*)d_in[0];
    const float* target  = (const float*)d_in[1];
    float* out = (float*)d_out;
    int batch = in_sizes[1] / (NOBJ * 5);            // 16384
    int nblocks = (batch + WAVES - 1) / WAVES;       // 4096
    hipMemsetAsync(out, 0, sizeof(float), stream);
    yolo_loss_wave<<<nblocks, BLOCK, 0, stream>>>(outputs, target, out, batch, 1.0f / (float)batch);
}

// Round 9
// 151.287 us; speedup vs baseline: 1.1576x; 1.1576x over previous
//
#include <hip/hip_runtime.h>
#include <math.h>

#define GRID_CELLS 49
#define NOBJ 10
#define BB 2
#define NCLS 20
#define OUT_C 30   // 5*BB + NCLS
#define LAMBDA_C 5.0f
#define LAMBDA_N 0.5f
#define BLOCK 256
#define ITEMS 5    // batch items per group (5*49 = 245 loss threads)
#define CELLW 10

// r9: r6 structure + (1) register prefetch of row data before preproc,
// (2) wave-0 shuffle-based preproc with per-cell occupancy masks (no gt
// zeroing, no metadata barrier), (3) 2048 resident grid-stride blocks.
__global__ __launch_bounds__(BLOCK, 4) void yolo_loss_v9(
    const float* __restrict__ outputs,
    const float* __restrict__ target,
    float* __restrict__ out,
    int batch, float inv_batch, int ngroups)
{
    __shared__ float gt[ITEMS][GRID_CELLS][CELLW];   // 9800 B, never zeroed
    __shared__ unsigned int msk[ITEMS][4];           // m0lo,m0hi,m1lo,m1hi
    __shared__ float red[BLOCK / 64];

    const int t = threadIdx.x;
    const int wv = t >> 6;
    const int lane = t & 63;

    float acc = 0.0f;

    for (int grp = blockIdx.x; grp < ngroups; grp += gridDim.x) {
        const int b0 = grp * ITEMS;
        const int li = t / GRID_CELLS;
        const int c  = t - li * GRID_CELLS;
        const int b  = b0 + li;
        const bool isLoss = (t < ITEMS * GRID_CELLS) && (b < batch);

        // ---- (1) prefetch this thread's 30-float row into registers ----
        float2 rv[15];
        if (isLoss) {
            const float2* r2 = reinterpret_cast<const float2*>(
                outputs + (size_t)(b * GRID_CELLS + c) * OUT_C);
            #pragma unroll
            for (int i = 0; i < 15; ++i) rv[i] = r2[i];
        }

        // ---- (2) wave 0: preproc 50 objects, slot + masks via shuffles ----
        if (wv == 0) {
            const int o   = lane % NOBJ;
            const int pli = lane / NOBJ;
            const int pb  = b0 + pli;
            float t0 = 0.f, t1 = 0.f, t2f = 0.f, t3f = 0.f, t4 = 0.f;
            int cell = 0, nz = 0;
            if (lane < ITEMS * NOBJ && pb < batch) {
                const float* tp = target + (size_t)pb * (NOBJ * 5) + o * 5;
                t0 = tp[0]; t1 = tp[1];
                t2f = sqrtf(tp[2]); t3f = sqrtf(tp[3]);
                t4 = tp[4];
                if (t0 != t0)   t0  = -1.0f;
                if (t1 != t1)   t1  = -1.0f;
                if (t2f != t2f) t2f = -1.0f;
                if (t3f != t3f) t3f = -1.0f;
                if (t4 != t4)   t4  = -1.0f;
                int xi = (int)truncf(7.0f * t0);
                int yi = (int)truncf(7.0f * t1);
                cell = 7 * yi + xi;
                cell = cell < 0 ? 0 : (cell > GRID_CELLS - 1 ? GRID_CELLS - 1 : cell);
                bool valid = (t0 != -1.0f) && (xi >= 0);
                float s5 = t0 + t1 + t2f + t3f + t4;
                nz = (valid && (s5 > 0.0f)) ? 1 : 0;
            }
            // slot = count of prior nz objects of same item with same cell
            int packed = cell | (nz << 8);
            int slot = 0;
            #pragma unroll
            for (int p = 0; p < NOBJ - 1; ++p) {
                int pk = __shfl(packed, lane - o + p, 64);
                if (p < o && (pk >> 8) && (pk & 0xff) == cell) slot++;
            }
            // per-item occupancy masks (49-bit in 2x u32), OR-reduce to o==0
            unsigned int m0lo = 0, m0hi = 0, m1lo = 0, m1hi = 0;
            if (nz) {
                if (cell < 32) m0lo = 1u << cell; else m0hi = 1u << (cell - 32);
                if (slot == 1) {
                    if (cell < 32) m1lo = 1u << cell; else m1hi = 1u << (cell - 32);
                }
            }
            #pragma unroll
            for (int off = 1; off < 16; off <<= 1) {
                unsigned int a = __shfl(m0lo, lane + off, 64);
                unsigned int bq = __shfl(m0hi, lane + off, 64);
                unsigned int cq = __shfl(m1lo, lane + off, 64);
                unsigned int dq = __shfl(m1hi, lane + off, 64);
                if (o + off < NOBJ) { m0lo |= a; m0hi |= bq; m1lo |= cq; m1hi |= dq; }
            }
            if (lane < ITEMS * NOBJ && pb < batch && o == 0) {
                msk[pli][0] = m0lo; msk[pli][1] = m0hi;
                msk[pli][2] = m1lo; msk[pli][3] = m1hi;
            }
            if (lane < ITEMS * NOBJ && pb < batch && nz && slot < BB) {
                gt[pli][cell][slot * 5 + 0] = t0;
                gt[pli][cell][slot * 5 + 1] = t1;
                gt[pli][cell][slot * 5 + 2] = t2f;
                gt[pli][cell][slot * 5 + 3] = t3f;
                gt[pli][cell][slot * 5 + 4] = t4;
            }
        }
        __syncthreads();   // BARRIER A: gt/msk ready; prefetch drained here too

        if (isLoss) {
            const unsigned int m0lo = msk[li][0], m0hi = msk[li][1];
            const unsigned int m1lo = msk[li][2], m1hi = msk[li][3];
            const bool has0 = (c < 32) ? ((m0lo >> c) & 1u) : ((m0hi >> (c - 32)) & 1u);
            const bool has1 = (c < 32) ? ((m1lo >> c) & 1u) : ((m1hi >> (c - 32)) & 1u);
            float g[BB][5];
            #pragma unroll
            for (int d = 0; d < 5; ++d) g[0][d] = has0 ? gt[li][c][d] : 0.0f;
            #pragma unroll
            for (int d = 0; d < 5; ++d) g[1][d] = has1 ? gt[li][c][5 + d] : 0.0f;

            // ---- loss math: verbatim from the absmax-0.0 kernel ----
            float pred[BB][5];
            {
                float2 p0 = rv[0], p1 = rv[1], p2 = rv[2], p3 = rv[3], p4 = rv[4];
                pred[0][0] = p0.x; pred[0][1] = p0.y; pred[0][2] = p1.x; pred[0][3] = p1.y; pred[0][4] = p2.x;
                pred[1][0] = p2.y; pred[1][1] = p3.x; pred[1][2] = p3.y; pred[1][3] = p4.x; pred[1][4] = p4.y;
            }
            float maxp; int cls;
            {
                float2 q0 = rv[5];
                maxp = q0.x; cls = 0;
                if (q0.y > maxp) { maxp = q0.y; cls = 1; }
                #pragma unroll
                for (int i = 1; i < NCLS / 2; ++i) {
                    float2 q = rv[5 + i];
                    if (q.x > maxp) { maxp = q.x; cls = 2 * i; }
                    if (q.y > maxp) { maxp = q.y; cls = 2 * i + 1; }
                }
            }
            float fcls = (float)cls;

            float pminx[BB], pmaxx[BB], pminy[BB], pmaxy[BB], parea[BB];
            #pragma unroll
            for (int p = 0; p < BB; ++p) {
                float sw = sqrtf(pred[p][2]);
                float sh = sqrtf(pred[p][3]);
                float w2 = sw * sw, h2 = sh * sh;
                pminx[p] = pred[p][0] - w2; pmaxx[p] = pred[p][0] + w2;
                pminy[p] = pred[p][1] - h2; pmaxy[p] = pred[p][1] + h2;
                parea[p] = fabsf(pmaxx[p] - pminx[p]) * fabsf(pmaxy[p] - pminy[p]);
            }
            float gminx[BB], gmaxx[BB], gminy[BB], gmaxy[BB], garea[BB];
            #pragma unroll
            for (int s = 0; s < BB; ++s) {
                float w2 = g[s][2] * g[s][2], h2 = g[s][3] * g[s][3];
                gminx[s] = g[s][0] - w2; gmaxx[s] = g[s][0] + w2;
                gminy[s] = g[s][1] - h2; gmaxy[s] = g[s][1] + h2;
                garea[s] = fabsf(gmaxx[s] - gminx[s]) * fabsf(gmaxy[s] - gminy[s]);
            }
            int t_index[BB];
            #pragma unroll
            for (int s = 0; s < BB; ++s) {
                float best = 0.0f; int bi = 0;
                #pragma unroll
                for (int p = 0; p < BB; ++p) {
                    float ix0 = fmaxf(gminx[s], pminx[p]);
                    float iy0 = fmaxf(gminy[s], pminy[p]);
                    float ix1 = fminf(gmaxx[s], pmaxx[p]);
                    float iy1 = fminf(gmaxy[s], pmaxy[p]);
                    float dx = fmaxf(ix1 - ix0, 0.0f);
                    float dy = fmaxf(iy1 - iy0, 0.0f);
                    float inter = dx * dy;
                    float uni = garea[s] + parea[p] - inter;
                    float iou = (uni == 0.0f) ? 0.0f : inter / uni;
                    if (p == 0) { best = iou; bi = 0; }
                    else if (iou > best) { best = iou; bi = p; }
                }
                t_index[s] = bi;
            }

            float lsum = 0.0f;
            #pragma unroll
            for (int s = 0; s < BB; ++s) {
                float ga[5];
                #pragma unroll
                for (int d = 0; d < 5; ++d) ga[d] = (t_index[s] == 0) ? g[0][d] : g[1][d];
                float r1w = pred[s][2] * pred[s][2], r1h = pred[s][3] * pred[s][3];
                float r2w = ga[2] * ga[2],           r2h = ga[3] * ga[3];
                float min1x = pred[s][0] - 0.5f * r1w, max1x = pred[s][0] + 0.5f * r1w;
                float min1y = pred[s][1] - 0.5f * r1h, max1y = pred[s][1] + 0.5f * r1h;
                float min2x = ga[0] - 0.5f * r2w, max2x = ga[0] + 0.5f * r2w;
                float min2y = ga[1] - 0.5f * r2h, max2y = ga[1] + 0.5f * r2h;
                float dx = fmaxf(fminf(max1x, max2x) - fmaxf(min1x, min2x), 0.0f);
                float dy = fmaxf(fminf(max1y, max2y) - fmaxf(min1y, min2y), 0.0f);
                float inter2 = dx * dy;
                float uni2 = r1w * r1h + r2w * r2h - inter2;
                float conf;
                if (truncf(uni2) == 0.0f || truncf(inter2) == 0.0f) conf = 0.0f;
                else conf = truncf(inter2 / (uni2 == 0.0f ? 1.0f : uni2));
                #pragma unroll
                for (int d = 0; d < 4; ++d) {
                    float df = ga[d] - pred[s][d];
                    lsum += LAMBDA_C * df * df;
                }
                { float df = conf - pred[s][4]; lsum += df * df; }
                float m = 1.0f;
                if (b == batch - 1 && s == t_index[BB - 1]) m = 0.0f;
                float dn = (pred[s][4] - conf) * m;
                lsum += LAMBDA_N * dn * dn;
                float predn = maxp * pred[s][4];
                float truth = (conf == fcls) ? 1.0f : 0.0f;
                float sum5 = ga[0] + ga[1] + ga[2] + ga[3] + conf;
                float cm = (sum5 > 0.0f) ? 1.0f : ((sum5 < 0.0f) ? -1.0f : 0.0f);
                float dcl = truth - predn;
                lsum += cm * dcl * dcl;
            }
            acc += lsum;
        }
        __syncthreads();   // BARRIER B: protect gt/msk before next iteration
    }

    // ---- block reduction: wave shuffle -> LDS -> one atomic per block ----
    #pragma unroll
    for (int off = 32; off > 0; off >>= 1) acc += __shfl_down(acc, off, 64);
    if (lane == 0) red[wv] = acc;
    __syncthreads();
    if (t == 0) {
        float s = 0.0f;
        #pragma unroll
        for (int v = 0; v < BLOCK / 64; ++v) s += red[v];
        atomicAdd(out, s * inv_batch);
    }
}

extern "C" void kernel_launch(void* const* d_in, const int* in_sizes, int n_in,
                              void* d_out, int out_size, void* d_ws, size_t ws_size,
                              hipStream_t stream) {
    const float* outputs = (const float*)d_in[0];
    const float* target  = (const float*)d_in[1];
    float* out = (float*)d_out;
    int batch = in_sizes[1] / (NOBJ * 5);             // 16384
    int ngroups = (batch + ITEMS - 1) / ITEMS;        // 3277
    int nblocks = ngroups < 2048 ? ngroups : 2048;    // all resident (8/CU)
    hipMemsetAsync(out, 0, sizeof(float), stream);
    yolo_loss_v9<<<nblocks, BLOCK, 0, stream>>>(outputs, target, out, batch,
                                                1.0f / (float)batch, ngroups);
}